// Round 13
// baseline (139.990 us; speedup 1.0000x reference)
//
#include <hip/hip_runtime.h>

// DDPM fused forward: per-sample 3x3 circular blur -> conv1(1->64) + t -> relu
// -> conv2(64->1) -> MSE vs original x.  B=64, C=1, H=W=128, HID=64.
//
// R5 structure: 256 blocks x 512 threads (2 waves/SIMD), 2x4 patch/thread.
// KEY CHANGE vs R4: no loop-invariant register array. R1-R4 all showed the
// allocator parks any big invariant array out of arch VGPRs (VGPR_Count 68/44,
// ~1.8x VALU instruction inflation ~ one move per operand use; asm-pin no-op).
// Now each channel RE-READS its 6 patch rows from LDS (12 x ds_read_b128,
// LDS pipe, same addresses every iteration) through a rolling 3-row window;
// h rows are consumed into acc immediately. Peak live ~70 floats with no
// large invariant array -> nothing to park. Loads issue one row ahead so
// ds_read latency hides under the 66-FMA row compute.

#define XS_W 72   // 70x70 x-tile (halo 3), padded stride
#define XB_W 72   // 68x68 blurred tile (halo 2), stride padded to 16B multiple

#define LDROW(W, k)                                                            \
    {                                                                          \
        const float4 _lo = *reinterpret_cast<const float4*>(&xb[py0 + (k)][px0]);     \
        const float4 _hi = *reinterpret_cast<const float4*>(&xb[py0 + (k)][px0 + 4]); \
        W[0] = _lo.x; W[1] = _lo.y; W[2] = _lo.z; W[3] = _lo.w;                \
        W[4] = _hi.x; W[5] = _hi.y; W[6] = _hi.z; W[7] = _hi.w;                \
    }

// hrow[j] = relu(hinit + rowneg + colneg[j] + 3x3 taps over rows A,B,C)
#define HROW(A, B, C, RN)                                                      \
    {                                                                          \
        const float _hb = hinit + (RN);                                        \
        _Pragma("unroll")                                                      \
        for (int j = 0; j < 6; ++j) {                                          \
            float vv = _hb + colneg[j];                                        \
            vv = fmaf(u0, A[j    ], vv);                                       \
            vv = fmaf(u1, A[j + 1], vv);                                       \
            vv = fmaf(u2, A[j + 2], vv);                                       \
            vv = fmaf(u3, B[j    ], vv);                                       \
            vv = fmaf(u4, B[j + 1], vv);                                       \
            vv = fmaf(u5, B[j + 2], vv);                                       \
            vv = fmaf(u6, C[j    ], vv);                                       \
            vv = fmaf(u7, C[j + 1], vv);                                       \
            vv = fmaf(u8, C[j + 2], vv);                                       \
            hrow[j] = fmaxf(vv, 0.f);                                          \
        }                                                                      \
    }

// accumulate hrow (h row index i) into output row OY with tap-row D2 = i-OY
#define ACCROW(OY, D2)                                                         \
    {                                                                          \
        const float _a0 = vw[3 * (D2)], _a1 = vw[3 * (D2) + 1],                \
                    _a2 = vw[3 * (D2) + 2];                                    \
        _Pragma("unroll")                                                      \
        for (int ox = 0; ox < 4; ++ox) {                                       \
            float a = acc[OY][ox];                                             \
            a = fmaf(_a0, hrow[ox    ], a);                                    \
            a = fmaf(_a1, hrow[ox + 1], a);                                    \
            a = fmaf(_a2, hrow[ox + 2], a);                                    \
            acc[OY][ox] = a;                                                   \
        }                                                                      \
    }

__global__ __launch_bounds__(512, 2) void ddpm_fused(
    const float* __restrict__ x, const int* __restrict__ t,
    const float* __restrict__ kernels, const float* __restrict__ w1,
    const float* __restrict__ b1, const float* __restrict__ w2,
    const float* __restrict__ b2, float* __restrict__ out)
{
    __shared__ __align__(16) float xs[70][XS_W];
    __shared__ __align__(16) float xb[68][XB_W];
    __shared__ float redbuf[8];

    const int bid = blockIdx.x;
    const int s   = bid >> 2;         // sample
    const int tt  = bid & 3;          // tile within sample (2x2 of 64x64)
    const int ty  = (tt >> 1) * 64;
    const int tx  = (tt & 1) * 64;
    const int tid = threadIdx.x;

    const float* __restrict__ xsamp = x + s * (128 * 128);

    // ---- block-uniform scalars ----
    const int   tb = t[s];
    const float tn = (float)(tb + 1) * 0.01f;           // (t+1)/n_T
    const float* __restrict__ kb = kernels + tb * 9;
    const float k0 = kb[0], k1 = kb[1], k2 = kb[2],
                k3 = kb[3], k4 = kb[4], k5 = kb[5],
                k6 = kb[6], k7 = kb[7], k8 = kb[8];

    // ---- phase A: stage x tile + halo 3 (circular wrap; 128 = pow2) ----
    for (int i = tid; i < 70 * 70; i += 512) {
        int r = i / 70, c = i - r * 70;
        int gy = (ty + r - 3) & 127;
        int gx = (tx + c - 3) & 127;
        xs[r][c] = xsamp[gy * 128 + gx];
    }
    __syncthreads();

    // ---- phase B: blur -> xb (tile-local rows -2..65), zero outside image ----
    for (int i = tid; i < 68 * 68; i += 512) {
        int r = i / 68, c = i - r * 68;
        int gy = ty + r - 2, gx = tx + c - 2;
        float v = 0.f;
        if (gy >= 0 && gy < 128 && gx >= 0 && gx < 128) {
            v = k0 * xs[r][c];
            v = fmaf(k1, xs[r    ][c + 1], v);
            v = fmaf(k2, xs[r    ][c + 2], v);
            v = fmaf(k3, xs[r + 1][c    ], v);
            v = fmaf(k4, xs[r + 1][c + 1], v);
            v = fmaf(k5, xs[r + 1][c + 2], v);
            v = fmaf(k6, xs[r + 2][c    ], v);
            v = fmaf(k7, xs[r + 2][c + 1], v);
            v = fmaf(k8, xs[r + 2][c + 2], v);
        }
        xb[r][c] = v;
    }
    __syncthreads();

    // ---- phase C: rolling-window channel loop ----
    // 32 patch-rows x 16 patch-cols thread grid; patch = 2 rows x 4 cols.
    const int ry = tid >> 4, rx = tid & 15;   // ry 0..31, rx 0..15
    const int py0 = ry * 2, px0 = rx * 4;     // tile-local output origin

    // h-position validity as additive bias: valid -> 0, invalid -> -1e30
    float rowneg[4], colneg[6];
#pragma unroll
    for (int i = 0; i < 4; ++i) {
        int gy = ty + py0 - 1 + i;
        rowneg[i] = (gy >= 0 && gy < 128) ? 0.f : -1e30f;
    }
#pragma unroll
    for (int j = 0; j < 6; ++j) {
        int gx = tx + px0 - 1 + j;
        colneg[j] = (gx >= 0 && gx < 128) ? 0.f : -1e30f;
    }

    float acc[2][4];
#pragma unroll
    for (int a = 0; a < 2; ++a)
#pragma unroll
        for (int b_ = 0; b_ < 4; ++b_) acc[a][b_] = 0.f;

#pragma unroll 1
    for (int c = 0; c < 64; ++c) {
        const float* __restrict__ w1c = w1 + c * 9;
        const float* __restrict__ w2c = w2 + c * 9;
        const float hinit = b1[c] + tn;
        const float u0 = w1c[0], u1 = w1c[1], u2 = w1c[2],
                    u3 = w1c[3], u4 = w1c[4], u5 = w1c[5],
                    u6 = w1c[6], u7 = w1c[7], u8 = w1c[8];
        float vw[9];
#pragma unroll
        for (int k = 0; k < 9; ++k) vw[k] = w2c[k];

        // rolling window over the 6 patch rows; rows re-read from LDS each
        // channel (addresses invariant), one row loaded ahead of its use.
        float W0[8], W1[8], W2[8], W3[8], W4[8], W5[8];
        float hrow[6];

        LDROW(W0, 0)
        LDROW(W1, 1)
        LDROW(W2, 2)
        LDROW(W3, 3)          // in flight during i=0 compute
        HROW(W0, W1, W2, rowneg[0])          // i = 0
        ACCROW(0, 0)
        LDROW(W4, 4)          // in flight during i=1 compute
        HROW(W1, W2, W3, rowneg[1])          // i = 1
        ACCROW(0, 1)
        ACCROW(1, 0)
        LDROW(W5, 5)          // in flight during i=2 compute
        HROW(W2, W3, W4, rowneg[2])          // i = 2
        ACCROW(0, 2)
        ACCROW(1, 1)
        HROW(W3, W4, W5, rowneg[3])          // i = 3
        ACCROW(1, 2)
    }

    // ---- epilogue: MSE vs original x (still in xs), block reduce ----
    const float b2v = b2[0];
    float sum = 0.f;
#pragma unroll
    for (int oy = 0; oy < 2; ++oy)
#pragma unroll
        for (int ox = 0; ox < 4; ++ox) {
            float recon = acc[oy][ox] + b2v;
            float xv = xs[py0 + oy + 3][px0 + ox + 3];
            float d = xv - recon;
            sum = fmaf(d, d, sum);
        }

#pragma unroll
    for (int off = 32; off > 0; off >>= 1)
        sum += __shfl_down(sum, off, 64);

    const int lane = tid & 63, wv = tid >> 6;
    if (lane == 0) redbuf[wv] = sum;
    __syncthreads();
    if (tid == 0) {
        float tot = redbuf[0] + redbuf[1] + redbuf[2] + redbuf[3]
                  + redbuf[4] + redbuf[5] + redbuf[6] + redbuf[7];
        atomicAdd(out, tot * (1.f / 1048576.f));   // /(64*128*128)
    }
}

extern "C" void kernel_launch(void* const* d_in, const int* in_sizes, int n_in,
                              void* d_out, int out_size, void* d_ws, size_t ws_size,
                              hipStream_t stream) {
    const float* x       = (const float*)d_in[0];
    const int*   t       = (const int*)  d_in[1];
    const float* kernels = (const float*)d_in[2];
    const float* w1      = (const float*)d_in[3];
    const float* b1      = (const float*)d_in[4];
    const float* w2      = (const float*)d_in[5];
    const float* b2      = (const float*)d_in[6];
    float* out = (float*)d_out;

    hipMemsetAsync(out, 0, sizeof(float), stream);
    ddpm_fused<<<256, 512, 0, stream>>>(x, t, kernels, w1, b1, w2, b2, out);
}